// Round 2
// baseline (2205.290 us; speedup 1.0000x reference)
//
#include <hip/hip_runtime.h>
#include <hip/hip_bf16.h>
#include <math.h>

#ifndef M_PI
#define M_PI 3.14159265358979323846
#endif

// Problem constants
#define NN 10000      // nodes
#define NE 160000     // edges
#define NC 16         // channels (in = hid = out)
#define NQ 5          // 2*order+1
#define NFR 10        // N_FREQ * N_RINGS = 5*2
#define CQ 80         // NC*NQ
#define OP 80         // NC*NQ outputs per node
#define WSZ 64000     // NC*NC*NQ*NQ*NFR

// ---------------------------------------------------------------------------
// Reorder W[o,c,p,q,f,r] -> Wr[fr][cq][op]   (fr=f*2+r, cq=c*5+q, op=o*5+p)
// ---------------------------------------------------------------------------
__global__ void reorder_w(const float* __restrict__ W1, const float* __restrict__ W2,
                          float* __restrict__ Wr1, float* __restrict__ Wr2) {
    int i = blockIdx.x * blockDim.x + threadIdx.x;
    if (i >= WSZ) return;
    int fr = i / 6400;
    int rem = i % 6400;
    int cq = rem / OP;
    int op = rem % OP;
    int c = cq / NQ, q = cq % NQ;
    int o = op / NQ, p = op % NQ;
    int f = fr / 2, r = fr % 2;
    int src = ((((o * NC + c) * NQ + p) * NQ + q) * 5 + f) * 2 + r;
    Wr1[i] = W1[src];
    Wr2[i] = W2[src];
}

// ---------------------------------------------------------------------------
// Self-interaction + bias: y[n,op] = sum_{cq} x[n,cq] * Ws[o,c,p,q] + (p==0)*b[o]
// Writes y fully (serves as the init before edge atomics).
// ---------------------------------------------------------------------------
__global__ void selfint(const float* __restrict__ xin, const float* __restrict__ Ws,
                        const float* __restrict__ b, float* __restrict__ y) {
    __shared__ float ws_s[NC * NC * NQ * NQ];  // 6400 floats = 25.6 KB
    int tid = threadIdx.x;
    for (int i = tid; i < NC * NC * NQ * NQ; i += blockDim.x) ws_s[i] = Ws[i];
    __syncthreads();
    int idx = blockIdx.x * blockDim.x + tid;     // over N*80 = 800000
    if (idx >= NN * OP) return;
    int n = idx / OP, op = idx % OP;
    int o = op / NQ, p = op % NQ;
    const float* xrow = xin + n * CQ;
    float acc = (p == 0) ? b[o] : 0.0f;
    #pragma unroll
    for (int c = 0; c < NC; ++c) {
        #pragma unroll
        for (int q = 0; q < NQ; ++q) {
            // Ws[o][c][p][q] = o*400 + c*25 + p*5 + q
            acc = fmaf(xrow[c * NQ + q], ws_s[o * 400 + c * 25 + p * 5 + q], acc);
        }
    }
    y[idx] = acc;
}

// ---------------------------------------------------------------------------
// Edge conv: per edge e (one lane per edge):
//   xt = transport(x[src], phi_e)                     (order 2)
//   msg[op] = sum_{fr} t[fr] * sum_{cq} xt[cq] * Wr[fr][cq][op]
//   atomicAdd into y[dst*80 + op]
// edge_index arrives as int32 (harness converts all integer inputs to int32).
// ---------------------------------------------------------------------------
__global__ __launch_bounds__(64, 2)
void edge_conv(const float* __restrict__ xin, const int* __restrict__ ei,
               const float* __restrict__ pre, const float* __restrict__ phi_arr,
               const float* __restrict__ Wr, float* __restrict__ y) {
    __shared__ float xt_s[CQ][64];   // 20 KB; stride 64 words -> free 2-way aliasing
    int tid = threadIdx.x;
    int e = blockIdx.x * 64 + tid;
    if (e >= NE) return;

    int src = ei[2 * e];
    int dst = ei[2 * e + 1];
    float ph = phi_arr[e];
    float s1, c1;
    sincosf(ph, &s1, &c1);
    float c2 = c1 * c1 - s1 * s1;
    float s2 = 2.0f * c1 * s1;

    // Load x[src] (80 floats, 16B-aligned) and transport into LDS column
    float v[CQ];
    const float4* xp = (const float4*)(xin + (long long)src * CQ);
    #pragma unroll
    for (int k = 0; k < CQ / 4; ++k) {
        float4 t4 = xp[k];
        v[4 * k + 0] = t4.x; v[4 * k + 1] = t4.y;
        v[4 * k + 2] = t4.z; v[4 * k + 3] = t4.w;
    }
    #pragma unroll
    for (int c = 0; c < NC; ++c) {
        float a0 = v[c * NQ + 0];
        float a1 = v[c * NQ + 1], b1v = v[c * NQ + 2];
        float a2 = v[c * NQ + 3], b2v = v[c * NQ + 4];
        xt_s[c * NQ + 0][tid] = a0;
        xt_s[c * NQ + 1][tid] = c1 * a1 - s1 * b1v;
        xt_s[c * NQ + 2][tid] = s1 * a1 + c1 * b1v;
        xt_s[c * NQ + 3][tid] = c2 * a2 - s2 * b2v;
        xt_s[c * NQ + 4][tid] = s2 * a2 + c2 * b2v;
    }

    float t[NFR];
    #pragma unroll
    for (int j = 0; j < NFR; ++j) t[j] = pre[(long long)e * NFR + j];

    float acc[OP];
    #pragma unroll
    for (int j = 0; j < OP; ++j) acc[j] = 0.0f;

    // Main contraction: W accesses are wave-uniform -> scalar loads from L2
    #pragma unroll
    for (int fr = 0; fr < NFR; ++fr) {
        const float tf = t[fr];
        const float* __restrict__ wb = Wr + fr * 6400;
        #pragma unroll 1
        for (int cq = 0; cq < CQ; ++cq) {
            float u = xt_s[cq][tid] * tf;
            const float* __restrict__ w = wb + cq * OP;
            #pragma unroll
            for (int op = 0; op < OP; ++op) {
                acc[op] = fmaf(u, w[op], acc[op]);
            }
        }
    }

    float* yd = y + (long long)dst * OP;
    #pragma unroll
    for (int op = 0; op < OP; ++op) atomicAdd(yd + op, acc[op]);
}

// ---------------------------------------------------------------------------
// Regular nonlinearity (Fourier -> 7 samples -> ReLU -> Fourier), optional
// residual add on the input coefficients. One thread per (n,c).
// ---------------------------------------------------------------------------
__global__ void nonlin(const float* __restrict__ yin, const float* __restrict__ res,
                       float* __restrict__ out) {
    int idx = blockIdx.x * blockDim.x + threadIdx.x;  // over N*C = 160000
    if (idx >= NN * NC) return;
    const float* vp = yin + (long long)idx * NQ;
    float a0 = vp[0], a1 = vp[1], a2 = vp[2], a3 = vp[3], a4 = vp[4];
    if (res != nullptr) {
        const float* rp = res + (long long)idx * NQ;
        a0 += rp[0]; a1 += rp[1]; a2 += rp[2]; a3 += rp[3]; a4 += rp[4];
    }
    float o0 = 0.f, o1 = 0.f, o2 = 0.f, o3 = 0.f, o4 = 0.f;
    #pragma unroll
    for (int k = 0; k < 7; ++k) {
        float th = (float)(2.0 * M_PI / 7.0) * (float)k;
        float c1k = cosf(th), s1k = sinf(th);
        float c2k = cosf(2.0f * th), s2k = sinf(2.0f * th);
        float s = a0 + a1 * c1k + a2 * s1k + a3 * c2k + a4 * s2k;
        s = fmaxf(s, 0.0f);
        o0 += s;
        o1 += s * c1k; o2 += s * s1k;
        o3 += s * c2k; o4 += s * s2k;
    }
    const float i7 = 1.0f / 7.0f, t7 = 2.0f / 7.0f;
    float* op = out + (long long)idx * NQ;
    op[0] = o0 * i7;
    op[1] = o1 * t7; op[2] = o2 * t7;
    op[3] = o3 * t7; op[4] = o4 * t7;
}

// ---------------------------------------------------------------------------
extern "C" void kernel_launch(void* const* d_in, const int* in_sizes, int n_in,
                              void* d_out, int out_size, void* d_ws, size_t ws_size,
                              hipStream_t stream) {
    const float* x    = (const float*)d_in[0];
    const int*   ei   = (const int*)d_in[1];      // int inputs arrive as int32
    const float* pre  = (const float*)d_in[2];
    const float* phi  = (const float*)d_in[3];
    const float* W1   = (const float*)d_in[4];
    const float* b1   = (const float*)d_in[5];
    const float* Ws1  = (const float*)d_in[6];
    const float* W2   = (const float*)d_in[7];
    const float* b2   = (const float*)d_in[8];
    const float* Ws2  = (const float*)d_in[9];
    float* out = (float*)d_out;

    // Workspace layout (floats)
    float* ws   = (float*)d_ws;
    float* Wr1  = ws;                     // 64000
    float* Wr2  = Wr1 + WSZ;              // 64000
    float* y1   = Wr2 + WSZ;              // 800000  (also reused as y2)
    float* h    = y1 + (size_t)NN * OP;   // 800000
    // total: 1,728,000 floats = 6.9 MB

    reorder_w<<<(WSZ + 255) / 256, 256, 0, stream>>>(W1, W2, Wr1, Wr2);

    // Layer 1
    selfint<<<(NN * OP + 255) / 256, 256, 0, stream>>>(x, Ws1, b1, y1);
    edge_conv<<<NE / 64, 64, 0, stream>>>(x, ei, pre, phi, Wr1, y1);
    nonlin<<<(NN * NC + 255) / 256, 256, 0, stream>>>(y1, nullptr, h);

    // Layer 2 (reuse y1 buffer as y2)
    selfint<<<(NN * OP + 255) / 256, 256, 0, stream>>>(h, Ws2, b2, y1);
    edge_conv<<<NE / 64, 64, 0, stream>>>(h, ei, pre, phi, Wr2, y1);

    // Residual + final nonlinearity -> d_out
    nonlin<<<(NN * NC + 255) / 256, 256, 0, stream>>>(y1, x, out);
}

// Round 3
// 2190.011 us; speedup vs baseline: 1.0070x; 1.0070x over previous
//
#include <hip/hip_runtime.h>
#include <hip/hip_bf16.h>
#include <math.h>

#ifndef M_PI
#define M_PI 3.14159265358979323846
#endif

// Problem constants
#define NN 10000      // nodes
#define NE 160000     // edges
#define NC 16         // channels (in = hid = out)
#define NQ 5          // 2*order+1
#define NFR 10        // N_FREQ * N_RINGS = 5*2
#define CQ 80         // NC*NQ
#define OP 80         // NC*NQ outputs per node
#define WSZ 64000     // NC*NC*NQ*NQ*NFR

// ---------------------------------------------------------------------------
// Reorder W[o,c,p,q,f,r] -> Wr[fr][cq][op]   (fr=f*2+r, cq=c*5+q, op=o*5+p)
// ---------------------------------------------------------------------------
__global__ void reorder_w(const float* __restrict__ W1, const float* __restrict__ W2,
                          float* __restrict__ Wr1, float* __restrict__ Wr2) {
    int i = blockIdx.x * blockDim.x + threadIdx.x;
    if (i >= WSZ) return;
    int fr = i / 6400;
    int rem = i % 6400;
    int cq = rem / OP;
    int op = rem % OP;
    int c = cq / NQ, q = cq % NQ;
    int o = op / NQ, p = op % NQ;
    int f = fr / 2, r = fr % 2;
    int src = ((((o * NC + c) * NQ + p) * NQ + q) * 5 + f) * 2 + r;
    Wr1[i] = W1[src];
    Wr2[i] = W2[src];
}

// ---------------------------------------------------------------------------
// Self-interaction + bias: y[n,op] = sum_{cq} x[n,cq] * Ws[o,c,p,q] + (p==0)*b[o]
// Writes y fully (serves as the init before edge atomics).
// ---------------------------------------------------------------------------
__global__ void selfint(const float* __restrict__ xin, const float* __restrict__ Ws,
                        const float* __restrict__ b, float* __restrict__ y) {
    __shared__ float ws_s[NC * NC * NQ * NQ];  // 6400 floats = 25.6 KB
    int tid = threadIdx.x;
    for (int i = tid; i < NC * NC * NQ * NQ; i += blockDim.x) ws_s[i] = Ws[i];
    __syncthreads();
    int idx = blockIdx.x * blockDim.x + tid;     // over N*80 = 800000
    if (idx >= NN * OP) return;
    int n = idx / OP, op = idx % OP;
    int o = op / NQ, p = op % NQ;
    const float* xrow = xin + n * CQ;
    float acc = (p == 0) ? b[o] : 0.0f;
    #pragma unroll
    for (int c = 0; c < NC; ++c) {
        #pragma unroll
        for (int q = 0; q < NQ; ++q) {
            acc = fmaf(xrow[c * NQ + q], ws_s[o * 400 + c * 25 + p * 5 + q], acc);
        }
    }
    y[idx] = acc;
}

// ---------------------------------------------------------------------------
// Edge conv v2: one lane per edge, 256-thread blocks (NE = 625 * 256 exactly).
// fr outermost; W[fr] slice (6400 floats = 25.6 KB) staged in LDS per block,
// read via wave-uniform broadcast (conflict-free, not BW-bound). Source row
// re-read per (fr,c) from global (L1-hot) + transport recomputed — avoids the
// per-lane LDS column array that capped occupancy at R1.
// ---------------------------------------------------------------------------
__global__ __launch_bounds__(256, 4)
void edge_conv(const float* __restrict__ xin, const int* __restrict__ ei,
               const float* __restrict__ pre, const float* __restrict__ phi_arr,
               const float* __restrict__ Wr, float* __restrict__ y) {
    __shared__ float w_s[6400];   // 25.6 KB
    const int tid = threadIdx.x;
    const int e = blockIdx.x * 256 + tid;   // exact fit: no guard, no early return

    const int src = ei[2 * e];
    const int dst = ei[2 * e + 1];
    float s1, c1;
    sincosf(phi_arr[e], &s1, &c1);
    const float c2 = c1 * c1 - s1 * s1;
    const float s2 = 2.0f * c1 * s1;

    float acc[OP];
    #pragma unroll
    for (int j = 0; j < OP; ++j) acc[j] = 0.0f;

    const float* xrow = xin + (size_t)src * CQ;
    const float4* wsrc = (const float4*)Wr;

    for (int fr = 0; fr < NFR; ++fr) {
        __syncthreads();   // protect previous iteration's w_s reads
        // Cooperative stage of W[fr]: 1600 float4s across 256 threads
        for (int i = tid; i < 1600; i += 256) {
            ((float4*)w_s)[i] = wsrc[fr * 1600 + i];
        }
        __syncthreads();

        const float tf = pre[e * NFR + fr];  // coalesced, L1/L2-hot after fr=0

        #pragma unroll 1
        for (int c = 0; c < NC; ++c) {
            const float a0  = xrow[c * NQ + 0];
            const float a1  = xrow[c * NQ + 1];
            const float b1v = xrow[c * NQ + 2];
            const float a2  = xrow[c * NQ + 3];
            const float b2v = xrow[c * NQ + 4];
            float u[NQ];
            u[0] = a0 * tf;
            u[1] = (c1 * a1 - s1 * b1v) * tf;
            u[2] = (s1 * a1 + c1 * b1v) * tf;
            u[3] = (c2 * a2 - s2 * b2v) * tf;
            u[4] = (s2 * a2 + c2 * b2v) * tf;
            const float* __restrict__ wb = w_s + c * NQ * OP;
            #pragma unroll
            for (int q = 0; q < NQ; ++q) {
                #pragma unroll
                for (int op = 0; op < OP; ++op) {
                    acc[op] = fmaf(u[q], wb[q * OP + op], acc[op]);
                }
            }
        }
    }

    float* yd = y + (size_t)dst * OP;
    #pragma unroll
    for (int op = 0; op < OP; ++op) atomicAdd(yd + op, acc[op]);
}

// ---------------------------------------------------------------------------
// Regular nonlinearity (Fourier -> 7 samples -> ReLU -> Fourier), optional
// residual add on the input coefficients. One thread per (n,c).
// ---------------------------------------------------------------------------
__global__ void nonlin(const float* __restrict__ yin, const float* __restrict__ res,
                       float* __restrict__ out) {
    int idx = blockIdx.x * blockDim.x + threadIdx.x;  // over N*C = 160000
    if (idx >= NN * NC) return;
    const float* vp = yin + (long long)idx * NQ;
    float a0 = vp[0], a1 = vp[1], a2 = vp[2], a3 = vp[3], a4 = vp[4];
    if (res != nullptr) {
        const float* rp = res + (long long)idx * NQ;
        a0 += rp[0]; a1 += rp[1]; a2 += rp[2]; a3 += rp[3]; a4 += rp[4];
    }
    float o0 = 0.f, o1 = 0.f, o2 = 0.f, o3 = 0.f, o4 = 0.f;
    #pragma unroll
    for (int k = 0; k < 7; ++k) {
        float th = (float)(2.0 * M_PI / 7.0) * (float)k;
        float c1k = cosf(th), s1k = sinf(th);
        float c2k = cosf(2.0f * th), s2k = sinf(2.0f * th);
        float s = a0 + a1 * c1k + a2 * s1k + a3 * c2k + a4 * s2k;
        s = fmaxf(s, 0.0f);
        o0 += s;
        o1 += s * c1k; o2 += s * s1k;
        o3 += s * c2k; o4 += s * s2k;
    }
    const float i7 = 1.0f / 7.0f, t7 = 2.0f / 7.0f;
    float* op = out + (long long)idx * NQ;
    op[0] = o0 * i7;
    op[1] = o1 * t7; op[2] = o2 * t7;
    op[3] = o3 * t7; op[4] = o4 * t7;
}

// ---------------------------------------------------------------------------
extern "C" void kernel_launch(void* const* d_in, const int* in_sizes, int n_in,
                              void* d_out, int out_size, void* d_ws, size_t ws_size,
                              hipStream_t stream) {
    const float* x    = (const float*)d_in[0];
    const int*   ei   = (const int*)d_in[1];      // int inputs arrive as int32
    const float* pre  = (const float*)d_in[2];
    const float* phi  = (const float*)d_in[3];
    const float* W1   = (const float*)d_in[4];
    const float* b1   = (const float*)d_in[5];
    const float* Ws1  = (const float*)d_in[6];
    const float* W2   = (const float*)d_in[7];
    const float* b2   = (const float*)d_in[8];
    const float* Ws2  = (const float*)d_in[9];
    float* out = (float*)d_out;

    // Workspace layout (floats)
    float* ws   = (float*)d_ws;
    float* Wr1  = ws;                     // 64000
    float* Wr2  = Wr1 + WSZ;              // 64000
    float* y1   = Wr2 + WSZ;              // 800000  (also reused as y2)
    float* h    = y1 + (size_t)NN * OP;   // 800000
    // total: 1,728,000 floats = 6.9 MB

    reorder_w<<<(WSZ + 255) / 256, 256, 0, stream>>>(W1, W2, Wr1, Wr2);

    // Layer 1
    selfint<<<(NN * OP + 255) / 256, 256, 0, stream>>>(x, Ws1, b1, y1);
    edge_conv<<<NE / 256, 256, 0, stream>>>(x, ei, pre, phi, Wr1, y1);
    nonlin<<<(NN * NC + 255) / 256, 256, 0, stream>>>(y1, nullptr, h);

    // Layer 2 (reuse y1 buffer as y2)
    selfint<<<(NN * OP + 255) / 256, 256, 0, stream>>>(h, Ws2, b2, y1);
    edge_conv<<<NE / 256, 256, 0, stream>>>(h, ei, pre, phi, Wr2, y1);

    // Residual + final nonlinearity -> d_out
    nonlin<<<(NN * NC + 255) / 256, 256, 0, stream>>>(y1, x, out);
}